// Round 17
// baseline (229.282 us; speedup 1.0000x reference)
//
#include <hip/hip_runtime.h>
#include <hip/hip_bf16.h>
#include <stdint.h>

// ---------------------------------------------------------------------------
// Problem constants
// ---------------------------------------------------------------------------
#define NCLS   6
#define NATOMS 5
#define B_     64
#define P_     196
#define D_     768
#define H_     3072
#define SEQ    (NCLS + P_)        // 202
#define NPATCH (B_ * P_)          // 12544
#define NPAIR  (B_ * NCLS)        // 384

typedef unsigned short ushort_t;
typedef __attribute__((ext_vector_type(8))) short  bf16x8;
typedef __attribute__((ext_vector_type(4))) float  f32x4;

// ---------------------------------------------------------------------------
// Helpers
// ---------------------------------------------------------------------------
// fast tanh-form GELU (max abs err ~1e-3; threshold budget 3.98e-2)
__device__ __forceinline__ float gelu_fast(float x) {
    float x2 = x * x;
    float y  = x * (1.59576912f + 0.07135482f * x2);
    float e  = __expf(y);
    return x * e / (e + 1.0f);
}

__device__ __forceinline__ ushort_t f2bf(float f) {
    uint32_t u = __builtin_bit_cast(uint32_t, f);
    u = (u + 0x7fffu + ((u >> 16) & 1u)) >> 16;
    return (ushort_t)u;
}

__device__ __forceinline__ void gload16(const ushort_t* g, ushort_t* l) {
    __builtin_amdgcn_global_load_lds(
        (const __attribute__((address_space(1))) uint32_t*)g,
        (__attribute__((address_space(3))) uint32_t*)l,
        16, 0, 0);
}

// ---------------------------------------------------------------------------
// prep kernel: ONLY kernelA's dependencies — w1 + aiw conversions, x split,
// gate.  (w2/aow conversions moved into kernelA's tail: consumed by kernelB.)
// 256 threads/block, 1024 elems/block.
// ---------------------------------------------------------------------------
#define P_W1E   (H_ * D_ / 1024)                    // w1:   2304
#define P_AIE   (P_W1E + NATOMS * H_ * D_ / 1024)   // +aiw: 13824
#define P_XE    (P_AIE + B_ * SEQ * D_ / 1024)      // +x:   23520
#define PREP_NB (P_XE + NPAIR / 4)                  // +gate: 23616

__global__ void prep_kernel(const float* __restrict__ w1, ushort_t* __restrict__ o1,
                            const float* __restrict__ aiw, ushort_t* __restrict__ o3,
                            const float* __restrict__ x, ushort_t* __restrict__ xp,
                            ushort_t* __restrict__ cls,
                            const float* __restrict__ gd,
                            int* __restrict__ srcA, int* __restrict__ dstA,
                            float* __restrict__ wgtA) {
    int bid = blockIdx.x;
    if (bid < P_AIE) {
        const float* src; ushort_t* dst; int i;
        if (bid < P_W1E) { src = w1;  dst = o1; i = bid * 1024; }
        else             { src = aiw; dst = o3; i = (bid - P_W1E) * 1024; }
        i += threadIdx.x * 4;
        float4 v = *(const float4*)(src + i);
        ushort4 o;
        o.x = f2bf(v.x); o.y = f2bf(v.y); o.z = f2bf(v.z); o.w = f2bf(v.w);
        *(ushort4*)(dst + i) = o;
    } else if (bid < P_XE) {
        int i = (bid - P_AIE) * 1024 + threadIdx.x * 4;
        int row = i / D_;
        int col = i - row * D_;
        int b = row / SEQ, s = row - b * SEQ;
        float4 v = *(const float4*)(x + i);
        ushort4 o;
        o.x = f2bf(v.x); o.y = f2bf(v.y); o.z = f2bf(v.z); o.w = f2bf(v.w);
        if (s < NCLS) {
            *(ushort4*)(cls + (size_t)(b * NCLS + s) * D_ + col) = o;
        } else {
            *(ushort4*)(xp + (size_t)(b * P_ + (s - NCLS)) * D_ + col) = o;
        }
    } else {
        // gate: one wave per (b, n) pair
        int r = (bid - P_XE) * 4 + (threadIdx.x >> 6);
        int lane = threadIdx.x & 63;
        int b = r / NCLS, n = r - b * NCLS;
        const float* xr = x + (size_t)(b * SEQ + n) * D_;
        const float* g  = gd + (size_t)n * D_;
        float s = 0.f;
        for (int k = lane; k < D_; k += 64) s += xr[k] * g[k];
        #pragma unroll
        for (int off = 32; off > 0; off >>= 1) s += __shfl_down(s, off, 64);
        if (lane == 0) {
            float logit = s;
            bool left = (logit >= 0.f);
            float p = 1.f / (1.f + expf(-logit));
            float w = left ? p : (1.f - p);
            const int LK[NCLS] = {3, 4, 8, 9, 13, 14};
            const int RK[NCLS] = {15, 20, 16, 21, 17, 22};
            int key = left ? LK[n] : RK[n];
            srcA[r] = key / NATOMS;
            dstA[r] = key % NATOMS;
            wgtA[r] = w;
        }
    }
}

// ===========================================================================
// GEMM core (proven r9/r15 machinery): BK=64 2-phase counted-vmcnt, 128x128
// tile, 8 waves (2M x 4N), 64 KB LDS -> 2 blk/CU, VMW(4), LDS swizzle
// slot^=(row>>1)&3 (0 bank conflicts).  564 TF @ K=768 — at the documented
// 2-phase structural ceiling (m230/m233).
// MODE 0: H1 = bf16(gelu(acc + b1[n]))
// MODE 1: out[(b*SEQ+NCLS+p)*D_+n] = acc + b2[n]
// MODE 2: if src[m]==atom: HID[m*N+n] = bf16(gelu(acc + aib[atom*H_+n]))
// MODE 3: if dst[m]==atom: out[(b*SEQ+nn)*D_+n] = (acc + aob[atom*D_+n])*wgt[m]
// ===========================================================================
template <int ROWS, int NT>
__device__ __forceinline__ void stage_t32(const ushort_t* __restrict__ gpanel, int K,
                                          int kbase, ushort_t* lds, int tid) {
    constexpr int LOADS = ROWS * 4 / NT;
    static_assert(LOADS * NT == ROWS * 4, "stage divisibility");
    #pragma unroll
    for (int l = 0; l < LOADS; ++l) {
        int c = l * NT + tid;
        int row = c >> 2;
        int col = ((c & 3) ^ ((row >> 1) & 3)) << 3;
        gload16(gpanel + (size_t)row * K + kbase + col, lds + ((size_t)c << 3));
    }
}

#define BAR     asm volatile("s_barrier" ::: "memory")
#define VMW(N)  asm volatile("s_waitcnt vmcnt(" #N ")" ::: "memory")

#define STAGE64T(T, DB) \
    stage_t32<128, 512>(Ab, K, ((T) << 6),      &LA[DB][0][0], tid); \
    stage_t32<128, 512>(Bb, K, ((T) << 6),      &LB[DB][0][0], tid); \
    stage_t32<128, 512>(Ab, K, ((T) << 6) + 32, &LA[DB][1][0], tid); \
    stage_t32<128, 512>(Bb, K, ((T) << 6) + 32, &LB[DB][1][0], tid);

#define COMPUTE64(DB) do { \
    __builtin_amdgcn_s_setprio(1); \
    _Pragma("unroll") \
    for (int ks = 0; ks < 2; ++ks) { \
        bf16x8 bfr[1]; \
        bfr[0] = *(const bf16x8*)(&LB[DB][ks][bbase]); \
        _Pragma("unroll") \
        for (int mh = 0; mh < 2; ++mh) { \
            bf16x8 afr[2]; \
            afr[0] = *(const bf16x8*)(&LA[DB][ks][abase + mh * 1024]); \
            afr[1] = *(const bf16x8*)(&LA[DB][ks][abase + mh * 1024 + 512]); \
            _Pragma("unroll") \
            for (int mi = 0; mi < 2; ++mi) \
                acc[mh * 2 + mi][0] = __builtin_amdgcn_mfma_f32_16x16x32_bf16( \
                    afr[mi], bfr[0], acc[mh * 2 + mi][0], 0, 0, 0); \
        } \
    } \
    __builtin_amdgcn_s_setprio(0); \
    __builtin_amdgcn_sched_barrier(0); \
} while (0)

template <int MODE>
__device__ __forceinline__ void gemm_core(char* SMEMc, int tile_m, int tile_n, int atom,
        const ushort_t* __restrict__ A, const ushort_t* __restrict__ Bm,
        int N, int K,
        const float* __restrict__ bias,
        float* __restrict__ outF, ushort_t* __restrict__ outB,
        const int* __restrict__ selIdx, const float* __restrict__ wgt) {
    // fixed config: BM=BN=128, WM=2, WN=4, NT=512
    typedef ushort_t lt[2][2][128 * 32];
    lt& LA = *(lt*)SMEMc;
    lt& LB = *(lt*)(SMEMc + sizeof(lt));

    const ushort_t* Ab = A  + (size_t)tile_m * 128 * K;
    const ushort_t* Bb = Bm + ((size_t)atom * N + (size_t)tile_n * 128) * K;

    const int tid  = threadIdx.x;
    const int lane = tid & 63;
    const int wave = tid >> 6;
    const int wr = wave >> 2;      // 0..1 : A rows [wr*64, +64)
    const int wc = wave & 3;       // 0..3 : B rows [wc*32, +32)

    const int frow = lane & 15;
    const int fsl  = lane >> 4;
    const int rbase = frow * 32 + ((fsl ^ ((frow >> 1) & 3)) << 3);
    const int abase = wr * 2048 + rbase;   // + mh*1024 + mi*512
    const int bbase = wc * 1024 + rbase;   // FN=2: + ni*512

    f32x4 acc[4][2];
    #pragma unroll
    for (int i = 0; i < 4; i++)
        #pragma unroll
        for (int j = 0; j < 2; j++)
            acc[i][j] = (f32x4){0.f, 0.f, 0.f, 0.f};

    // NOTE: FN is 2 (wave covers 32 B-rows = 2 frags).  COMPUTE64 above was
    // written for FN=1; use the full 2-frag version here:
    const int nkt = K >> 6;

#define COMPUTE64F(DB) do { \
    __builtin_amdgcn_s_setprio(1); \
    _Pragma("unroll") \
    for (int ks = 0; ks < 2; ++ks) { \
        bf16x8 bfr[2]; \
        bfr[0] = *(const bf16x8*)(&LB[DB][ks][bbase]); \
        bfr[1] = *(const bf16x8*)(&LB[DB][ks][bbase + 512]); \
        _Pragma("unroll") \
        for (int mh = 0; mh < 2; ++mh) { \
            bf16x8 afr[2]; \
            afr[0] = *(const bf16x8*)(&LA[DB][ks][abase + mh * 1024]); \
            afr[1] = *(const bf16x8*)(&LA[DB][ks][abase + mh * 1024 + 512]); \
            _Pragma("unroll") \
            for (int mi = 0; mi < 2; ++mi) \
                _Pragma("unroll") \
                for (int ni = 0; ni < 2; ++ni) \
                    acc[mh * 2 + mi][ni] = __builtin_amdgcn_mfma_f32_16x16x32_bf16( \
                        afr[mi], bfr[ni], acc[mh * 2 + mi][ni], 0, 0, 0); \
        } \
    } \
    __builtin_amdgcn_s_setprio(0); \
    __builtin_amdgcn_sched_barrier(0); \
} while (0)

    STAGE64T(0, 0)
    for (int tb = 0; tb < (nkt >> 1) - 1; ++tb) {
        STAGE64T(2 * tb + 1, 1)
        VMW(4); BAR;
        COMPUTE64F(0);
        BAR;
        STAGE64T(2 * tb + 2, 0)
        VMW(4); BAR;
        COMPUTE64F(1);
        BAR;
    }
    STAGE64T(nkt - 1, 1)
    VMW(4); BAR;
    COMPUTE64F(0);
    BAR;
    VMW(0); BAR;
    COMPUTE64F(1);
#undef COMPUTE64F

    // epilogue: C/D layout col = lane&15, row = (lane>>4)*4 + reg
    const int fq = lane >> 4;
    #pragma unroll
    for (int mi = 0; mi < 4; mi++) {
        #pragma unroll
        for (int ni = 0; ni < 2; ni++) {
            int n = tile_n * 128 + wc * 32 + ni * 16 + frow;
            float bn;
            if constexpr (MODE == 2)      bn = bias[atom * H_ + n];
            else if constexpr (MODE == 3) bn = bias[atom * D_ + n];
            else                          bn = bias[n];
            #pragma unroll
            for (int rr = 0; rr < 4; rr++) {
                int m = tile_m * 128 + wr * 64 + mi * 16 + fq * 4 + rr;
                float v = acc[mi][ni][rr];
                if constexpr (MODE == 0) {
                    outB[(size_t)m * N + n] = f2bf(gelu_fast(v + bn));
                } else if constexpr (MODE == 1) {
                    int b = m / P_, p = m - b * P_;
                    outF[(size_t)(b * SEQ + NCLS + p) * D_ + n] = v + bn;
                } else if constexpr (MODE == 2) {
                    if (selIdx[m] == atom)
                        outB[(size_t)m * N + n] = f2bf(gelu_fast(v + bn));
                } else { // MODE 3
                    if (selIdx[m] == atom) {
                        int b = m / NCLS, nn = m - b * NCLS;
                        outF[(size_t)(b * SEQ + nn) * D_ + n] = (v + bn) * wgt[m];
                    }
                }
            }
        }
    }
}

// ===========================================================================
// Merged launches.
// Kernel A regions (in dispatch order):
//   [0, 2352)            GEMM0 128x128 tiles (cohort decode 7m x 3n)
//   [2352, 2712)         cls-in: 3m x 24n x 5 atoms = 360 (swizzled core)
//   [2712, 3864)         w2 fp32->bf16 (1152 blocks x 2048 elems)
//   [3864, 9624)         aow fp32->bf16 (5760 blocks) — consumed by kernelB
// Kernel B regions:
//   [0, 588)             GEMM1 (cohort decode)
//   [588, 678)           cls-out: 3m x 6n x 5 atoms = 90
// ===========================================================================
#define G0_NB   2352
#define CIN_E   (G0_NB + 360)
#define W2C_E   (CIN_E + 1152)
#define AOWC_E  (W2C_E + 5760)
#define G1_NB   588
#define COUT_NB 90

// cohort decode for patch GEMMs (grid_m % 7 == 0, grid_n % 3 == 0)
__device__ __forceinline__ void cohort_decode(int bid, int nwg, int grid_m, int grid_n,
                                              int& tile_m, int& tile_n) {
    int q = nwg >> 3, r = nwg & 7;
    int xcd = bid & 7, slot = bid >> 3;
    int wg = (xcd < r ? xcd * (q + 1) : r * (q + 1) + (xcd - r) * q) + slot;
    int per_col = (grid_m / 7) * 21;
    int gn = wg / per_col;  int r1 = wg - gn * per_col;
    int gm = r1 / 21;       int ii = r1 - gm * 21;
    tile_m = gm * 7 + ii / 3;
    tile_n = gn * 3 + (ii - (ii / 3) * 3);
}

__global__ __launch_bounds__(512, 4)
void kernelA(const ushort_t* __restrict__ Xp, const ushort_t* __restrict__ W1b,
             const float* __restrict__ b1, ushort_t* __restrict__ H1,
             const ushort_t* __restrict__ CLSb, const ushort_t* __restrict__ AIWb,
             const float* __restrict__ aib, ushort_t* __restrict__ HID,
             const int* __restrict__ SRC,
             const float* __restrict__ w2, ushort_t* __restrict__ W2b,
             const float* __restrict__ aow, ushort_t* __restrict__ AOWb) {
    __shared__ __align__(16) char SMEM[65536];
    int bid = blockIdx.x;
    if (bid < G0_NB) {
        int tm, tn;
        cohort_decode(bid, G0_NB, 98, 24, tm, tn);
        gemm_core<0>(SMEM, tm, tn, 0, Xp, W1b, H_, D_, b1, nullptr, H1, nullptr, nullptr);
    } else if (bid < CIN_E) {
        int c = bid - G0_NB;
        int atom = c / 72;  int r1 = c - atom * 72;
        gemm_core<2>(SMEM, r1 / 24, r1 % 24, atom,
                     CLSb, AIWb, H_, D_, aib, nullptr, HID, SRC, nullptr);
    } else if (bid < W2C_E) {
        int i = (bid - CIN_E) * 2048 + threadIdx.x * 4;
        float4 v = *(const float4*)(w2 + i);
        ushort4 o;
        o.x = f2bf(v.x); o.y = f2bf(v.y); o.z = f2bf(v.z); o.w = f2bf(v.w);
        *(ushort4*)(W2b + i) = o;
    } else {
        int i = (bid - W2C_E) * 2048 + threadIdx.x * 4;
        float4 v = *(const float4*)(aow + i);
        ushort4 o;
        o.x = f2bf(v.x); o.y = f2bf(v.y); o.z = f2bf(v.z); o.w = f2bf(v.w);
        *(ushort4*)(AOWb + i) = o;
    }
}

__global__ __launch_bounds__(512, 4)
void kernelB(const ushort_t* __restrict__ H1, const ushort_t* __restrict__ W2b,
             const float* __restrict__ b2, float* __restrict__ out,
             const ushort_t* __restrict__ HID, const ushort_t* __restrict__ AOWb,
             const float* __restrict__ aob, const int* __restrict__ DST,
             const float* __restrict__ WGT) {
    __shared__ __align__(16) char SMEM[65536];
    int bid = blockIdx.x;
    if (bid < G1_NB) {
        int tm, tn;
        cohort_decode(bid, G1_NB, 98, 6, tm, tn);
        gemm_core<1>(SMEM, tm, tn, 0, H1, W2b, D_, H_, b2, out, nullptr, nullptr, nullptr);
    } else {
        int c = bid - G1_NB;
        int atom = c / 18;  int r1 = c - atom * 18;
        gemm_core<3>(SMEM, r1 / 6, r1 % 6, atom,
                     HID, AOWb, D_, H_, aob, out, nullptr, DST, WGT);
    }
}

// ---------------------------------------------------------------------------
// Launch
// ---------------------------------------------------------------------------
extern "C" void kernel_launch(void* const* d_in, const int* in_sizes, int n_in,
                              void* d_out, int out_size, void* d_ws, size_t ws_size,
                              hipStream_t stream) {
    const float* x   = (const float*)d_in[0];
    const float* w1  = (const float*)d_in[1];
    const float* b1  = (const float*)d_in[2];
    const float* w2  = (const float*)d_in[3];
    const float* b2  = (const float*)d_in[4];
    const float* gd  = (const float*)d_in[5];
    const float* aiw = (const float*)d_in[6];
    const float* aib = (const float*)d_in[7];
    const float* aow = (const float*)d_in[8];
    const float* aob = (const float*)d_in[9];
    float* out = (float*)d_out;

    char* ws = (char*)d_ws;
    ushort_t* Xp   = (ushort_t*)ws; ws += (size_t)NPATCH * D_ * 2;
    ushort_t* W1b  = (ushort_t*)ws; ws += (size_t)H_ * D_ * 2;
    ushort_t* W2b  = (ushort_t*)ws; ws += (size_t)D_ * H_ * 2;
    ushort_t* H1   = (ushort_t*)ws; ws += (size_t)NPATCH * H_ * 2;
    ushort_t* CLSb = (ushort_t*)ws; ws += (size_t)NPAIR * D_ * 2;
    ushort_t* AIWb = (ushort_t*)ws; ws += (size_t)NATOMS * H_ * D_ * 2;
    ushort_t* AOWb = (ushort_t*)ws; ws += (size_t)NATOMS * D_ * H_ * 2;
    ushort_t* HID  = (ushort_t*)ws; ws += (size_t)NPAIR * H_ * 2;
    int*   SRC = (int*)ws;   ws += NPAIR * 4;
    int*   DST = (int*)ws;   ws += NPAIR * 4;
    float* WGT = (float*)ws; ws += NPAIR * 4;

    // prep: only kernelA's deps (w1, aiw, x split, gate)
    prep_kernel<<<PREP_NB, 256, 0, stream>>>(w1, W1b, aiw, AIWb,
                                             x, Xp, CLSb, gd, SRC, DST, WGT);

    // kernel A: GEMM0 + cls-in + w2/aow conversions (tail-fill)
    kernelA<<<dim3(AOWC_E, 1, 1), 512, 0, stream>>>(
        Xp, W1b, b1, H1, CLSb, AIWb, aib, HID, SRC, w2, W2b, aow, AOWb);

    // kernel B: GEMM1 + cls-out (tail-fill)
    kernelB<<<dim3(G1_NB + COUT_NB, 1, 1), 512, 0, stream>>>(
        H1, W2b, b2, out, HID, AOWb, aob, DST, WGT);
}

// Round 18
// 223.613 us; speedup vs baseline: 1.0254x; 1.0254x over previous
//
#include <hip/hip_runtime.h>
#include <hip/hip_bf16.h>
#include <stdint.h>

// ---------------------------------------------------------------------------
// Problem constants
// ---------------------------------------------------------------------------
#define NCLS   6
#define NATOMS 5
#define B_     64
#define P_     196
#define D_     768
#define H_     3072
#define SEQ    (NCLS + P_)        // 202
#define NPATCH (B_ * P_)          // 12544
#define NPAIR  (B_ * NCLS)        // 384

typedef unsigned short ushort_t;
typedef __attribute__((ext_vector_type(8))) short  bf16x8;
typedef __attribute__((ext_vector_type(4))) float  f32x4;

// ---------------------------------------------------------------------------
// Helpers
// ---------------------------------------------------------------------------
// fast tanh-form GELU (max abs err ~1e-3; threshold budget 3.98e-2)
__device__ __forceinline__ float gelu_fast(float x) {
    float x2 = x * x;
    float y  = x * (1.59576912f + 0.07135482f * x2);
    float e  = __expf(y);
    return x * e / (e + 1.0f);
}

__device__ __forceinline__ ushort_t f2bf(float f) {
    uint32_t u = __builtin_bit_cast(uint32_t, f);
    u = (u + 0x7fffu + ((u >> 16) & 1u)) >> 16;
    return (ushort_t)u;
}

__device__ __forceinline__ void gload16(const ushort_t* g, ushort_t* l) {
    __builtin_amdgcn_global_load_lds(
        (const __attribute__((address_space(1))) uint32_t*)g,
        (__attribute__((address_space(3))) uint32_t*)l,
        16, 0, 0);
}

// ---------------------------------------------------------------------------
// prep kernel: all fp32->bf16 conversions (w1,w2,aiw,aow) + x split + gate.
// r17 lesson: conversion traffic is conserved wherever it lives; riding a
// busy GEMM's tail just serializes it there AND contends for HBM.  Keep it
// in the dedicated HBM-bound prep pass.
// ---------------------------------------------------------------------------
#define CVT_B1   (H_ * D_ / 1024)                     // w1:   2304
#define CVT_B2   (CVT_B1 + D_ * H_ / 1024)            // +w2:  4608
#define CVT_B3   (CVT_B2 + NATOMS * H_ * D_ / 1024)   // +aiw: 16128
#define CVT_B4   (CVT_B3 + NATOMS * D_ * H_ / 1024)   // +aow: 27648
#define PREP_XE  (CVT_B4 + B_ * SEQ * D_ / 1024)      // +x:   37344
#define PREP_NB  (PREP_XE + NPAIR / 4)                // +gate: 37440

__global__ void prep_kernel(const float* __restrict__ w1, ushort_t* __restrict__ o1,
                            const float* __restrict__ w2, ushort_t* __restrict__ o2,
                            const float* __restrict__ aiw, ushort_t* __restrict__ o3,
                            const float* __restrict__ aow, ushort_t* __restrict__ o4,
                            const float* __restrict__ x, ushort_t* __restrict__ xp,
                            ushort_t* __restrict__ cls,
                            const float* __restrict__ gd,
                            int* __restrict__ srcA, int* __restrict__ dstA,
                            float* __restrict__ wgtA) {
    int bid = blockIdx.x;
    if (bid < CVT_B4) {
        const float* src; ushort_t* dst; int i;
        if (bid < CVT_B1)      { src = w1;  dst = o1; i = bid * 1024; }
        else if (bid < CVT_B2) { src = w2;  dst = o2; i = (bid - CVT_B1) * 1024; }
        else if (bid < CVT_B3) { src = aiw; dst = o3; i = (bid - CVT_B2) * 1024; }
        else                   { src = aow; dst = o4; i = (bid - CVT_B3) * 1024; }
        i += threadIdx.x * 4;
        float4 v = *(const float4*)(src + i);
        ushort4 o;
        o.x = f2bf(v.x); o.y = f2bf(v.y); o.z = f2bf(v.z); o.w = f2bf(v.w);
        *(ushort4*)(dst + i) = o;
    } else if (bid < PREP_XE) {
        int i = (bid - CVT_B4) * 1024 + threadIdx.x * 4;
        int row = i / D_;
        int col = i - row * D_;
        int b = row / SEQ, s = row - b * SEQ;
        float4 v = *(const float4*)(x + i);
        ushort4 o;
        o.x = f2bf(v.x); o.y = f2bf(v.y); o.z = f2bf(v.z); o.w = f2bf(v.w);
        if (s < NCLS) {
            *(ushort4*)(cls + (size_t)(b * NCLS + s) * D_ + col) = o;
        } else {
            *(ushort4*)(xp + (size_t)(b * P_ + (s - NCLS)) * D_ + col) = o;
        }
    } else {
        // gate: one wave per (b, n) pair
        int r = (bid - PREP_XE) * 4 + (threadIdx.x >> 6);
        int lane = threadIdx.x & 63;
        int b = r / NCLS, n = r - b * NCLS;
        const float* xr = x + (size_t)(b * SEQ + n) * D_;
        const float* g  = gd + (size_t)n * D_;
        float s = 0.f;
        for (int k = lane; k < D_; k += 64) s += xr[k] * g[k];
        #pragma unroll
        for (int off = 32; off > 0; off >>= 1) s += __shfl_down(s, off, 64);
        if (lane == 0) {
            float logit = s;
            bool left = (logit >= 0.f);
            float p = 1.f / (1.f + expf(-logit));
            float w = left ? p : (1.f - p);
            const int LK[NCLS] = {3, 4, 8, 9, 13, 14};
            const int RK[NCLS] = {15, 20, 16, 21, 17, 22};
            int key = left ? LK[n] : RK[n];
            srcA[r] = key / NATOMS;
            dstA[r] = key % NATOMS;
            wgtA[r] = w;
        }
    }
}

// ===========================================================================
// GEMM core (proven r9/r15/r17 machinery): BK=64 2-phase counted-vmcnt,
// 128x128 tile, 8 waves (2M x 4N), 64 KB LDS -> 2 blk/CU, VMW(4), LDS
// swizzle slot^=(row>>1)&3 (0 bank conflicts).  564 TF @ K=768 — at the
// documented 2-phase structural ceiling (m230/m233).
// MODE 0: H1 = bf16(gelu(acc + b1[n]))
// MODE 1: out[(b*SEQ+NCLS+p)*D_+n] = acc + b2[n]
// MODE 2: if src[m]==atom: HID[m*N+n] = bf16(gelu(acc + aib[atom*H_+n]))
// MODE 3: if dst[m]==atom: out[(b*SEQ+nn)*D_+n] = (acc + aob[atom*D_+n])*wgt[m]
// ===========================================================================
template <int ROWS, int NT>
__device__ __forceinline__ void stage_t32(const ushort_t* __restrict__ gpanel, int K,
                                          int kbase, ushort_t* lds, int tid) {
    constexpr int LOADS = ROWS * 4 / NT;
    static_assert(LOADS * NT == ROWS * 4, "stage divisibility");
    #pragma unroll
    for (int l = 0; l < LOADS; ++l) {
        int c = l * NT + tid;
        int row = c >> 2;
        int col = ((c & 3) ^ ((row >> 1) & 3)) << 3;
        gload16(gpanel + (size_t)row * K + kbase + col, lds + ((size_t)c << 3));
    }
}

#define BAR     asm volatile("s_barrier" ::: "memory")
#define VMW(N)  asm volatile("s_waitcnt vmcnt(" #N ")" ::: "memory")

#define STAGE64T(T, DB) \
    stage_t32<128, 512>(Ab, K, ((T) << 6),      &LA[DB][0][0], tid); \
    stage_t32<128, 512>(Bb, K, ((T) << 6),      &LB[DB][0][0], tid); \
    stage_t32<128, 512>(Ab, K, ((T) << 6) + 32, &LA[DB][1][0], tid); \
    stage_t32<128, 512>(Bb, K, ((T) << 6) + 32, &LB[DB][1][0], tid);

template <int MODE>
__device__ __forceinline__ void gemm_core(char* SMEMc, int tile_m, int tile_n, int atom,
        const ushort_t* __restrict__ A, const ushort_t* __restrict__ Bm,
        int N, int K,
        const float* __restrict__ bias,
        float* __restrict__ outF, ushort_t* __restrict__ outB,
        const int* __restrict__ selIdx, const float* __restrict__ wgt) {
    // fixed config: BM=BN=128, WM=2, WN=4, NT=512
    typedef ushort_t lt[2][2][128 * 32];
    lt& LA = *(lt*)SMEMc;
    lt& LB = *(lt*)(SMEMc + sizeof(lt));

    const ushort_t* Ab = A  + (size_t)tile_m * 128 * K;
    const ushort_t* Bb = Bm + ((size_t)atom * N + (size_t)tile_n * 128) * K;

    const int tid  = threadIdx.x;
    const int lane = tid & 63;
    const int wave = tid >> 6;
    const int wr = wave >> 2;      // 0..1 : A rows [wr*64, +64)
    const int wc = wave & 3;       // 0..3 : B rows [wc*32, +32)

    const int frow = lane & 15;
    const int fsl  = lane >> 4;
    const int rbase = frow * 32 + ((fsl ^ ((frow >> 1) & 3)) << 3);
    const int abase = wr * 2048 + rbase;   // + mh*1024 + mi*512
    const int bbase = wc * 1024 + rbase;   // + ni*512

    f32x4 acc[4][2];
    #pragma unroll
    for (int i = 0; i < 4; i++)
        #pragma unroll
        for (int j = 0; j < 2; j++)
            acc[i][j] = (f32x4){0.f, 0.f, 0.f, 0.f};

    const int nkt = K >> 6;

#define COMPUTE64F(DB) do { \
    __builtin_amdgcn_s_setprio(1); \
    _Pragma("unroll") \
    for (int ks = 0; ks < 2; ++ks) { \
        bf16x8 bfr[2]; \
        bfr[0] = *(const bf16x8*)(&LB[DB][ks][bbase]); \
        bfr[1] = *(const bf16x8*)(&LB[DB][ks][bbase + 512]); \
        _Pragma("unroll") \
        for (int mh = 0; mh < 2; ++mh) { \
            bf16x8 afr[2]; \
            afr[0] = *(const bf16x8*)(&LA[DB][ks][abase + mh * 1024]); \
            afr[1] = *(const bf16x8*)(&LA[DB][ks][abase + mh * 1024 + 512]); \
            _Pragma("unroll") \
            for (int mi = 0; mi < 2; ++mi) \
                _Pragma("unroll") \
                for (int ni = 0; ni < 2; ++ni) \
                    acc[mh * 2 + mi][ni] = __builtin_amdgcn_mfma_f32_16x16x32_bf16( \
                        afr[mi], bfr[ni], acc[mh * 2 + mi][ni], 0, 0, 0); \
        } \
    } \
    __builtin_amdgcn_s_setprio(0); \
    __builtin_amdgcn_sched_barrier(0); \
} while (0)

    STAGE64T(0, 0)
    for (int tb = 0; tb < (nkt >> 1) - 1; ++tb) {
        STAGE64T(2 * tb + 1, 1)
        VMW(4); BAR;
        COMPUTE64F(0);
        BAR;
        STAGE64T(2 * tb + 2, 0)
        VMW(4); BAR;
        COMPUTE64F(1);
        BAR;
    }
    STAGE64T(nkt - 1, 1)
    VMW(4); BAR;
    COMPUTE64F(0);
    BAR;
    VMW(0); BAR;
    COMPUTE64F(1);
#undef COMPUTE64F

    // epilogue: C/D layout col = lane&15, row = (lane>>4)*4 + reg
    const int fq = lane >> 4;
    #pragma unroll
    for (int mi = 0; mi < 4; mi++) {
        #pragma unroll
        for (int ni = 0; ni < 2; ni++) {
            int n = tile_n * 128 + wc * 32 + ni * 16 + frow;
            float bn;
            if constexpr (MODE == 2)      bn = bias[atom * H_ + n];
            else if constexpr (MODE == 3) bn = bias[atom * D_ + n];
            else                          bn = bias[n];
            #pragma unroll
            for (int rr = 0; rr < 4; rr++) {
                int m = tile_m * 128 + wr * 64 + mi * 16 + fq * 4 + rr;
                float v = acc[mi][ni][rr];
                if constexpr (MODE == 0) {
                    outB[(size_t)m * N + n] = f2bf(gelu_fast(v + bn));
                } else if constexpr (MODE == 1) {
                    int b = m / P_, p = m - b * P_;
                    outF[(size_t)(b * SEQ + NCLS + p) * D_ + n] = v + bn;
                } else if constexpr (MODE == 2) {
                    if (selIdx[m] == atom)
                        outB[(size_t)m * N + n] = f2bf(gelu_fast(v + bn));
                } else { // MODE 3
                    if (selIdx[m] == atom) {
                        int b = m / NCLS, nn = m - b * NCLS;
                        outF[(size_t)(b * SEQ + nn) * D_ + n] = (v + bn) * wgt[m];
                    }
                }
            }
        }
    }
}

// ===========================================================================
// Merged launches (r16 composition + r17's conflict-free cls core).
// Kernel A: [0,2352) GEMM0 (cohort 7m x 3n) ; [2352,2712) cls-in 3x24x5.
// Kernel B: [0,588) GEMM1 (cohort) ; [588,678) cls-out 3x6x5.
// ===========================================================================
#define G0_NB   2352
#define CIN_NB  360
#define G1_NB   588
#define COUT_NB 90

// cohort decode for patch GEMMs (grid_m % 7 == 0, grid_n % 3 == 0)
__device__ __forceinline__ void cohort_decode(int bid, int nwg, int grid_m, int grid_n,
                                              int& tile_m, int& tile_n) {
    int q = nwg >> 3, r = nwg & 7;
    int xcd = bid & 7, slot = bid >> 3;
    int wg = (xcd < r ? xcd * (q + 1) : r * (q + 1) + (xcd - r) * q) + slot;
    int per_col = (grid_m / 7) * 21;
    int gn = wg / per_col;  int r1 = wg - gn * per_col;
    int gm = r1 / 21;       int ii = r1 - gm * 21;
    tile_m = gm * 7 + ii / 3;
    tile_n = gn * 3 + (ii - (ii / 3) * 3);
}

__global__ __launch_bounds__(512, 4)
void kernelA(const ushort_t* __restrict__ Xp, const ushort_t* __restrict__ W1b,
             const float* __restrict__ b1, ushort_t* __restrict__ H1,
             const ushort_t* __restrict__ CLSb, const ushort_t* __restrict__ AIWb,
             const float* __restrict__ aib, ushort_t* __restrict__ HID,
             const int* __restrict__ SRC) {
    __shared__ __align__(16) char SMEM[65536];
    int bid = blockIdx.x;
    if (bid < G0_NB) {
        int tm, tn;
        cohort_decode(bid, G0_NB, 98, 24, tm, tn);
        gemm_core<0>(SMEM, tm, tn, 0, Xp, W1b, H_, D_, b1, nullptr, H1, nullptr, nullptr);
    } else {
        int c = bid - G0_NB;
        int atom = c / 72;  int r1 = c - atom * 72;
        gemm_core<2>(SMEM, r1 / 24, r1 % 24, atom,
                     CLSb, AIWb, H_, D_, aib, nullptr, HID, SRC, nullptr);
    }
}

__global__ __launch_bounds__(512, 4)
void kernelB(const ushort_t* __restrict__ H1, const ushort_t* __restrict__ W2b,
             const float* __restrict__ b2, float* __restrict__ out,
             const ushort_t* __restrict__ HID, const ushort_t* __restrict__ AOWb,
             const float* __restrict__ aob, const int* __restrict__ DST,
             const float* __restrict__ WGT) {
    __shared__ __align__(16) char SMEM[65536];
    int bid = blockIdx.x;
    if (bid < G1_NB) {
        int tm, tn;
        cohort_decode(bid, G1_NB, 98, 6, tm, tn);
        gemm_core<1>(SMEM, tm, tn, 0, H1, W2b, D_, H_, b2, out, nullptr, nullptr, nullptr);
    } else {
        int c = bid - G1_NB;
        int atom = c / 18;  int r1 = c - atom * 18;
        gemm_core<3>(SMEM, r1 / 6, r1 % 6, atom,
                     HID, AOWb, D_, H_, aob, out, nullptr, DST, WGT);
    }
}

// ---------------------------------------------------------------------------
// Launch
// ---------------------------------------------------------------------------
extern "C" void kernel_launch(void* const* d_in, const int* in_sizes, int n_in,
                              void* d_out, int out_size, void* d_ws, size_t ws_size,
                              hipStream_t stream) {
    const float* x   = (const float*)d_in[0];
    const float* w1  = (const float*)d_in[1];
    const float* b1  = (const float*)d_in[2];
    const float* w2  = (const float*)d_in[3];
    const float* b2  = (const float*)d_in[4];
    const float* gd  = (const float*)d_in[5];
    const float* aiw = (const float*)d_in[6];
    const float* aib = (const float*)d_in[7];
    const float* aow = (const float*)d_in[8];
    const float* aob = (const float*)d_in[9];
    float* out = (float*)d_out;

    char* ws = (char*)d_ws;
    ushort_t* Xp   = (ushort_t*)ws; ws += (size_t)NPATCH * D_ * 2;
    ushort_t* W1b  = (ushort_t*)ws; ws += (size_t)H_ * D_ * 2;
    ushort_t* W2b  = (ushort_t*)ws; ws += (size_t)D_ * H_ * 2;
    ushort_t* H1   = (ushort_t*)ws; ws += (size_t)NPATCH * H_ * 2;
    ushort_t* CLSb = (ushort_t*)ws; ws += (size_t)NPAIR * D_ * 2;
    ushort_t* AIWb = (ushort_t*)ws; ws += (size_t)NATOMS * H_ * D_ * 2;
    ushort_t* AOWb = (ushort_t*)ws; ws += (size_t)NATOMS * D_ * H_ * 2;
    ushort_t* HID  = (ushort_t*)ws; ws += (size_t)NPAIR * H_ * 2;
    int*   SRC = (int*)ws;   ws += NPAIR * 4;
    int*   DST = (int*)ws;   ws += NPAIR * 4;
    float* WGT = (float*)ws; ws += NPAIR * 4;

    // prep: all conversions + x split + gate, one launch
    prep_kernel<<<PREP_NB, 256, 0, stream>>>(w1, W1b, w2, W2b, aiw, AIWb, aow, AOWb,
                                             x, Xp, CLSb, gd, SRC, DST, WGT);

    // kernel A: GEMM0 + cls-in (tail-fill, swizzled core)
    kernelA<<<dim3(G0_NB + CIN_NB, 1, 1), 512, 0, stream>>>(
        Xp, W1b, b1, H1, CLSb, AIWb, aib, HID, SRC);

    // kernel B: GEMM1 + cls-out (tail-fill, swizzled core)
    kernelB<<<dim3(G1_NB + COUT_NB, 1, 1), 512, 0, stream>>>(
        H1, W2b, b2, out, HID, AOWb, aob, DST, WGT);
}